// Round 12
// baseline (171.159 us; speedup 1.0000x reference)
//
#include <hip/hip_runtime.h>
#include <math.h>

#define EPS 1e-5f

typedef __attribute__((ext_vector_type(8))) short bf16x8;
typedef __attribute__((ext_vector_type(4))) float f32x4;

__device__ __forceinline__ ushort f2bf(float f) {
    union { float f; unsigned u; } v; v.f = f;
    unsigned u = v.u;
    return (ushort)((u + 0x7fffu + ((u >> 16) & 1u)) >> 16);  // RNE
}
__device__ __forceinline__ float bf2f(ushort h) {
    union { unsigned u; float f; } v; v.u = ((unsigned)h) << 16;
    return v.f;
}
// packed RNE f32->bf16x2 in one instruction (gfx950 v_cvt_pk_bf16_f32)
__device__ __forceinline__ uint cvtpk(float lo, float hi) {
    uint r;
    asm("v_cvt_pk_bf16_f32 %0, %1, %2" : "=v"(r) : "v"(lo), "v"(hi));
    return r;
}

// ---------------------------------------------------------------------------
// K0: fused prep — CSR row pointers for both graphs (boundary detection on
// sorted row arrays) + bf16 weight transposes + zero pad rows of msg1/msg2.
// ---------------------------------------------------------------------------
__global__ __launch_bounds__(256) void prep_all(
    const int* __restrict__ row1, int* __restrict__ ptr1, int E1,
    const int* __restrict__ row2, int* __restrict__ ptr2, int E2,
    const float* __restrict__ pw1, const float* __restrict__ pw2,
    const float* __restrict__ w1, const float* __restrict__ w2,
    ushort* __restrict__ wt1, ushort* __restrict__ wt2,
    ushort* __restrict__ wtl1, ushort* __restrict__ wtl2,
    ushort* __restrict__ m1z, ushort* __restrict__ m2z,
    int n, int B1, int B2)
{
    const int b = blockIdx.x;
    if (b < B1 + B2) {
        const int* row = (b < B1) ? row1 : row2;
        int* ptr = (b < B1) ? ptr1 : ptr2;
        const int E = (b < B1) ? E1 : E2;
        const int bb = (b < B1) ? b : b - B1;
        int e = bb * 256 + threadIdx.x;
        if (e >= E) return;
        int r = row[e];
        if (e == 0) {
            for (int j = 0; j <= r; ++j) ptr[j] = 0;
        }
        int rn = (e == E - 1) ? n : row[e + 1];
        for (int j = r + 1; j <= rn; ++j) ptr[j] = e + 1;
    } else {
        int idx = (b - B1 - B2) * 256 + threadIdx.x;
        if (idx < 16384) {
            int k = idx >> 6, j = idx & 63;
            wt1[j * 256 + k] = f2bf(pw1[idx]);
            wt2[j * 256 + k] = f2bf(pw2[idx]);
        }
        if (idx < 4096) {
            int k = idx >> 6, j = idx & 63;
            wtl1[j * 64 + k] = f2bf(w1[idx]);
            wtl2[j * 64 + k] = f2bf(w2[idx]);
        }
        if (idx < 64) {
            m1z[idx] = 0;
            m2z[idx] = 0;
        }
    }
}

// ---------------------------------------------------------------------------
// K1: msg1/msg2 = bf16(x @ W1/W2) via MFMA. One wave = 16 nodes (M=16,K=64,
// N=64). MFMA 16x16x32 layout (m89): A i=lane&15, k=(lane>>4)*8+e; B j=lane&15;
// D col=lane&15, row=(lane>>4)*4+reg. No LDS, no barriers.
// ---------------------------------------------------------------------------
__global__ __launch_bounds__(512) void linear_mfma(const float* __restrict__ x,
                                                   const ushort* __restrict__ wtl1,
                                                   const ushort* __restrict__ wtl2,
                                                   ushort* __restrict__ m1,
                                                   ushort* __restrict__ m2, int n)
{
    const int tid = threadIdx.x, wv = tid >> 6, lane = tid & 63;
    const int r = lane & 15, c = lane >> 4;
    const int nodebase = blockIdx.x * 128 + wv * 16;
    const int anode = nodebase + r;

    bf16x8 a[2];
#pragma unroll
    for (int kt = 0; kt < 2; ++kt) {
        float4 lo = {0.f, 0.f, 0.f, 0.f}, hi = {0.f, 0.f, 0.f, 0.f};
        if (anode < n) {
            lo = *(const float4*)&x[(size_t)anode * 64 + kt * 32 + c * 8];
            hi = *(const float4*)&x[(size_t)anode * 64 + kt * 32 + c * 8 + 4];
        }
        ushort t[8] = {f2bf(lo.x), f2bf(lo.y), f2bf(lo.z), f2bf(lo.w),
                       f2bf(hi.x), f2bf(hi.y), f2bf(hi.z), f2bf(hi.w)};
        a[kt] = *(const bf16x8*)t;
    }

    f32x4 acc1[4] = {{0.f,0.f,0.f,0.f},{0.f,0.f,0.f,0.f},
                     {0.f,0.f,0.f,0.f},{0.f,0.f,0.f,0.f}};
    f32x4 acc2[4] = {{0.f,0.f,0.f,0.f},{0.f,0.f,0.f,0.f},
                     {0.f,0.f,0.f,0.f},{0.f,0.f,0.f,0.f}};
#pragma unroll
    for (int kt = 0; kt < 2; ++kt) {
#pragma unroll
        for (int nt = 0; nt < 4; ++nt) {
            bf16x8 b1 = *(const bf16x8*)&wtl1[(nt * 16 + r) * 64 + kt * 32 + c * 8];
            bf16x8 b2 = *(const bf16x8*)&wtl2[(nt * 16 + r) * 64 + kt * 32 + c * 8];
            acc1[nt] = __builtin_amdgcn_mfma_f32_16x16x32_bf16(a[kt], b1, acc1[nt], 0, 0, 0);
            acc2[nt] = __builtin_amdgcn_mfma_f32_16x16x32_bf16(a[kt], b2, acc2[nt], 0, 0, 0);
        }
    }

#pragma unroll
    for (int e = 0; e < 4; ++e) {
        const int i = nodebase + c * 4 + e;
        if (i < n) {
#pragma unroll
            for (int nt = 0; nt < 4; ++nt) {
                m1[(size_t)i * 64 + nt * 16 + r] = f2bf(acc1[nt][e]);
                m2[(size_t)i * 64 + nt * 16 + r] = f2bf(acc2[nt][e]);
            }
        }
    }
}

// ---------------------------------------------------------------------------
// PNA aggregation (round-9 proven structure + short-batch path).
// Scalar (SGPR) col pipeline; invalid slots read zero row n.
// Full batch (rem>8):  lanes 0-31 = slots 0..7, lanes 32-63 = slots 8..15.
// Short batch (rem<=8): lanes 0-31 = slots 0..3, lanes 32-63 = slots 4..7
// (4 loads instead of 8 — cuts padding waste for ~33% of nodes at deg<=8).
// ---------------------------------------------------------------------------
__device__ __forceinline__ void agg_pass(const ushort* __restrict__ msg,
                                         const int* __restrict__ col,
                                         const ushort* __restrict__ wt,
                                         int rpv, ushort (*stw)[256],
                                         f32x4 acc[4],
                                         int nodebase, int lane, int n, int E)
{
    const int half = lane >> 5;
    const int l32 = lane & 31;
    const uint lanoff = (uint)l32 << 2;   // byte offset within a 128B row
    const int jbase8 = half << 3;         // 0 or 8
    const int jbase4 = half << 2;         // 0 or 4
    const char* msgc = (const char*)msg;

    for (int nn = 0; nn < 16; ++nn) {
        const int i = nodebase + nn;
        float s0 = 0.f, s1 = 0.f, q0 = 0.f, q1 = 0.f;
        float m0 = -INFINITY, m1v = -INFINITY;
        int cnt = 0;
        if (i < n) {
            const int e0 = __builtin_amdgcn_readlane(rpv, nn);
            const int e1 = __builtin_amdgcn_readlane(rpv, nn + 1);
            cnt = e1 - e0;
            for (int eb = e0; eb < e1; eb += 16) {
                const int rem = e1 - eb;
                if (rem <= 8) {  // wave-uniform short path
                    uint gv[4];
#pragma unroll
                    for (int t = 0; t < 4; ++t) {
                        int ilo = eb + t;     if (ilo > E - 1) ilo = E - 1;
                        int ihi = eb + t + 4; if (ihi > E - 1) ihi = E - 1;
                        const int rlo = (t < rem)     ? col[ilo] : n;
                        const int rhi = (t + 4 < rem) ? col[ihi] : n;
                        const int rsel = half ? rhi : rlo;
                        gv[t] = *(const uint*)(msgc + (((uint)rsel << 7) + lanoff));
                    }
#pragma unroll
                    for (int t = 0; t < 4; ++t) {
                        const bool valid = (jbase4 + t) < rem;
                        const float a = bf2f((ushort)(gv[t] & 0xffffu));
                        const float b = bf2f((ushort)(gv[t] >> 16));
                        s0 += a; q0 = fmaf(a, a, q0);
                        s1 += b; q1 = fmaf(b, b, q1);
                        m0  = fmaxf(m0,  valid ? a : -INFINITY);
                        m1v = fmaxf(m1v, valid ? b : -INFINITY);
                    }
                } else {
                    uint gv[8];
#pragma unroll
                    for (int t = 0; t < 8; ++t) {
                        int ilo = eb + t;     if (ilo > E - 1) ilo = E - 1;
                        int ihi = eb + t + 8; if (ihi > E - 1) ihi = E - 1;
                        const int rlo = (t < rem)     ? col[ilo] : n;
                        const int rhi = (t + 8 < rem) ? col[ihi] : n;
                        const int rsel = half ? rhi : rlo;
                        gv[t] = *(const uint*)(msgc + (((uint)rsel << 7) + lanoff));
                    }
#pragma unroll
                    for (int t = 0; t < 8; ++t) {
                        const bool valid = (jbase8 + t) < rem;
                        const float a = bf2f((ushort)(gv[t] & 0xffffu));
                        const float b = bf2f((ushort)(gv[t] >> 16));
                        s0 += a; q0 = fmaf(a, a, q0);
                        s1 += b; q1 = fmaf(b, b, q1);
                        m0  = fmaxf(m0,  valid ? a : -INFINITY);
                        m1v = fmaxf(m1v, valid ? b : -INFINITY);
                    }
                }
            }
        }
        s0 += __shfl_xor(s0, 32, 64);  s1 += __shfl_xor(s1, 32, 64);
        q0 += __shfl_xor(q0, 32, 64);  q1 += __shfl_xor(q1, 32, 64);
        m0  = fmaxf(m0,  __shfl_xor(m0, 32, 64));
        m1v = fmaxf(m1v, __shfl_xor(m1v, 32, 64));

        const float cf = (cnt > 0) ? (float)cnt : 1.f;
        const float inv = 1.f / cf;
        const float mean0 = s0 * inv, mean1 = s1 * inv;
        float v0 = q0 * inv - mean0 * mean0; if (v0 < 0.f) v0 = 0.f;
        float v1 = q1 * inv - mean1 * mean1; if (v1 < 0.f) v1 = 0.f;
        const float sd0 = sqrtf(v0 + EPS), sd1 = sqrtf(v1 + EPS);
        if (cnt == 0) { m0 = 0.f; m1v = 0.f; }

        char* rowp = (char*)&stw[nn][0];
        const int sw = (nn & 7) << 4;
        if (half == 0) {
            *(uint*)(rowp + ((0 + (int)lanoff) ^ sw))   = cvtpk(s0, s1);
            *(uint*)(rowp + ((256 + (int)lanoff) ^ sw)) = cvtpk(m0, m1v);
        } else {
            *(uint*)(rowp + ((128 + (int)lanoff) ^ sw)) = cvtpk(mean0, mean1);
            *(uint*)(rowp + ((384 + (int)lanoff) ^ sw)) = cvtpk(sd0, sd1);
        }
    }

    // MFMA combine (accumulates into acc)
    const int r = lane & 15, c = lane >> 4;
    const char* arow = (const char*)&stw[r][0];
    const int asw = (r & 7) << 4;
#pragma unroll
    for (int kt = 0; kt < 8; ++kt) {
        bf16x8 a = *(const bf16x8*)(arow + ((kt * 64 + c * 16) ^ asw));
#pragma unroll
        for (int nt = 0; nt < 4; ++nt) {
            bf16x8 b = *(const bf16x8*)&wt[(nt * 16 + r) * 256 + kt * 32 + c * 8];
            acc[nt] = __builtin_amdgcn_mfma_f32_16x16x32_bf16(a, b, acc[nt], 0, 0, 0);
        }
    }
}

// ---------------------------------------------------------------------------
// K2a: PNA pass 1 (graph 1): aggregate + MFMA, write bf16 partial.
// 2 waves/WG (128 thr, 16 KB LDS) -> 10 WGs/CU theoretical (occupancy probe).
// ---------------------------------------------------------------------------
__global__ __launch_bounds__(128) void pna_pass1(
    const ushort* __restrict__ msg, const int* __restrict__ rptr,
    const int* __restrict__ col, const ushort* __restrict__ wt,
    ushort* __restrict__ partial, int n, int E)
{
    __shared__ ushort st[2][16][256];  // 16 KB
    const int tid = threadIdx.x;
    const int wv = tid >> 6, lane = tid & 63;
    const int nodebase = blockIdx.x * 32 + wv * 16;

    int rpidx = nodebase + (lane & 31);
    if (rpidx > n) rpidx = n;
    const int rpv = rptr[rpidx];

    f32x4 acc[4] = {{0.f,0.f,0.f,0.f},{0.f,0.f,0.f,0.f},
                    {0.f,0.f,0.f,0.f},{0.f,0.f,0.f,0.f}};

    agg_pass(msg, col, wt, rpv, st[wv], acc, nodebase, lane, n, E);

    const int r = lane & 15, c = lane >> 4;
#pragma unroll
    for (int e = 0; e < 4; ++e) {
        const int i = nodebase + c * 4 + e;
        if (i < n) {
#pragma unroll
            for (int nt = 0; nt < 4; ++nt)
                partial[(size_t)i * 64 + nt * 16 + r] = f2bf(acc[nt][e]);
        }
    }
}

// ---------------------------------------------------------------------------
// K2b: PNA pass 2 (graph 2): aggregate + MFMA, add bf16 partial + biases,
// relu + LayerNorm, write final output.
// ---------------------------------------------------------------------------
__global__ __launch_bounds__(128) void pna_pass2(
    const ushort* __restrict__ msg, const int* __restrict__ rptr,
    const int* __restrict__ col, const ushort* __restrict__ wt,
    const float* __restrict__ b1, const float* __restrict__ b2,
    const float* __restrict__ gamma, const float* __restrict__ beta,
    const ushort* __restrict__ partial, float* __restrict__ out,
    int n, int E)
{
    __shared__ ushort st[2][16][256];  // 16 KB
    const int tid = threadIdx.x;
    const int wv = tid >> 6, lane = tid & 63;
    const int nodebase = blockIdx.x * 32 + wv * 16;

    int rpidx = nodebase + (lane & 31);
    if (rpidx > n) rpidx = n;
    const int rpv = rptr[rpidx];

    f32x4 acc[4] = {{0.f,0.f,0.f,0.f},{0.f,0.f,0.f,0.f},
                    {0.f,0.f,0.f,0.f},{0.f,0.f,0.f,0.f}};

    agg_pass(msg, col, wt, rpv, st[wv], acc, nodebase, lane, n, E);

    const int r = lane & 15, c = lane >> 4;
    float biasv[4], gmv[4], btv[4];
#pragma unroll
    for (int nt = 0; nt < 4; ++nt) {
        biasv[nt] = b1[nt * 16 + r] + b2[nt * 16 + r];
        gmv[nt] = gamma[nt * 16 + r];
        btv[nt] = beta[nt * 16 + r];
    }
#pragma unroll
    for (int e = 0; e < 4; ++e) {
        const int i = nodebase + c * 4 + e;
        float v[4];
        float sum = 0.f;
#pragma unroll
        for (int nt = 0; nt < 4; ++nt) {
            float t = 0.f;
            if (i < n)
                t = fmaxf(acc[nt][e] + biasv[nt] +
                          bf2f(partial[(size_t)i * 64 + nt * 16 + r]), 0.f);
            v[nt] = t;
            sum += t;
        }
        sum += __shfl_xor(sum, 1);
        sum += __shfl_xor(sum, 2);
        sum += __shfl_xor(sum, 4);
        sum += __shfl_xor(sum, 8);
        const float mu = sum * (1.f / 64.f);
        float sqs = 0.f;
#pragma unroll
        for (int nt = 0; nt < 4; ++nt) {
            float d = v[nt] - mu;
            sqs += d * d;
        }
        sqs += __shfl_xor(sqs, 1);
        sqs += __shfl_xor(sqs, 2);
        sqs += __shfl_xor(sqs, 4);
        sqs += __shfl_xor(sqs, 8);
        const float rs = rsqrtf(sqs * (1.f / 64.f) + EPS);
        if (i < n) {
#pragma unroll
            for (int nt = 0; nt < 4; ++nt)
                out[(size_t)i * 64 + nt * 16 + r] =
                    (v[nt] - mu) * rs * gmv[nt] + btv[nt];
        }
    }
}

// ---------------------------------------------------------------------------
extern "C" void kernel_launch(void* const* d_in, const int* in_sizes, int n_in,
                              void* d_out, int out_size, void* d_ws, size_t ws_size,
                              hipStream_t stream)
{
    const float* x     = (const float*)d_in[0];
    const float* w1    = (const float*)d_in[1];
    const float* w2    = (const float*)d_in[2];
    const float* pw1   = (const float*)d_in[3];
    const float* pb1   = (const float*)d_in[4];
    const float* pw2   = (const float*)d_in[5];
    const float* pb2   = (const float*)d_in[6];
    const float* gamma = (const float*)d_in[7];
    const float* beta  = (const float*)d_in[8];
    const int* nb_row  = (const int*)d_in[9];
    const int* nb_col  = (const int*)d_in[10];
    const int* cci_row = (const int*)d_in[11];
    const int* cci_col = (const int*)d_in[12];

    const int n  = in_sizes[0] / 64;   // 100000
    const int E1 = in_sizes[9];        // 1,000,000
    const int E2 = in_sizes[11];

    // workspace: msg1/msg2 bf16 [(n+1)*64] (row n = zeros) | ptr1/ptr2 [n+1] |
    //            wt1/wt2 [16384] | wtl1/wtl2 [4096] | partial bf16 [n*64]
    char* p = (char*)d_ws;
    ushort* msg1 = (ushort*)p;  p += (size_t)(n + 1) * 64 * sizeof(ushort);
    ushort* msg2 = (ushort*)p;  p += (size_t)(n + 1) * 64 * sizeof(ushort);
    int* ptr1 = (int*)p;        p += (size_t)(n + 1) * sizeof(int);
    int* ptr2 = (int*)p;        p += (size_t)(n + 1) * sizeof(int);
    p = (char*)(((uintptr_t)p + 63) & ~(uintptr_t)63);
    ushort* wt1 = (ushort*)p;   p += 16384 * sizeof(ushort);
    ushort* wt2 = (ushort*)p;   p += 16384 * sizeof(ushort);
    ushort* wtl1 = (ushort*)p;  p += 4096 * sizeof(ushort);
    ushort* wtl2 = (ushort*)p;  p += 4096 * sizeof(ushort);
    ushort* partial = (ushort*)p;
    float* outf = (float*)d_out;

    const int B1 = (E1 + 255) / 256, B2 = (E2 + 255) / 256;
    prep_all<<<B1 + B2 + 64, 256, 0, stream>>>(
        nb_row, ptr1, E1, cci_row, ptr2, E2,
        pw1, pw2, w1, w2, wt1, wt2, wtl1, wtl2,
        msg1 + (size_t)n * 64, msg2 + (size_t)n * 64, n, B1, B2);
    linear_mfma<<<(n + 127) / 128, 512, 0, stream>>>(x, wtl1, wtl2, msg1, msg2, n);

    const int grid = (n + 31) / 32;
    pna_pass1<<<grid, 128, 0, stream>>>(msg1, ptr1, nb_col, wt1, partial, n, E1);
    pna_pass2<<<grid, 128, 0, stream>>>(msg2, ptr2, cci_col, wt2,
                                        pb1, pb2, gamma, beta, partial, outf, n, E2);
}

// Round 13
// 162.718 us; speedup vs baseline: 1.0519x; 1.0519x over previous
//
#include <hip/hip_runtime.h>
#include <math.h>

#define EPS 1e-5f

typedef __attribute__((ext_vector_type(8))) short bf16x8;
typedef __attribute__((ext_vector_type(4))) float f32x4;

__device__ __forceinline__ ushort f2bf(float f) {
    union { float f; unsigned u; } v; v.f = f;
    unsigned u = v.u;
    return (ushort)((u + 0x7fffu + ((u >> 16) & 1u)) >> 16);  // RNE
}
__device__ __forceinline__ float bf2f(ushort h) {
    union { unsigned u; float f; } v; v.u = ((unsigned)h) << 16;
    return v.f;
}
// packed RNE f32->bf16x2 in one instruction (gfx950 v_cvt_pk_bf16_f32)
__device__ __forceinline__ uint cvtpk(float lo, float hi) {
    uint r;
    asm("v_cvt_pk_bf16_f32 %0, %1, %2" : "=v"(r) : "v"(lo), "v"(hi));
    return r;
}

// ---------------------------------------------------------------------------
// K0: fused prep — CSR row pointers for both graphs (boundary detection on
// sorted row arrays) + bf16 weight transposes + zero pad rows of msg1/msg2.
// ---------------------------------------------------------------------------
__global__ __launch_bounds__(256) void prep_all(
    const int* __restrict__ row1, int* __restrict__ ptr1, int E1,
    const int* __restrict__ row2, int* __restrict__ ptr2, int E2,
    const float* __restrict__ pw1, const float* __restrict__ pw2,
    const float* __restrict__ w1, const float* __restrict__ w2,
    ushort* __restrict__ wt1, ushort* __restrict__ wt2,
    ushort* __restrict__ wtl1, ushort* __restrict__ wtl2,
    ushort* __restrict__ m1z, ushort* __restrict__ m2z,
    int n, int B1, int B2)
{
    const int b = blockIdx.x;
    if (b < B1 + B2) {
        const int* row = (b < B1) ? row1 : row2;
        int* ptr = (b < B1) ? ptr1 : ptr2;
        const int E = (b < B1) ? E1 : E2;
        const int bb = (b < B1) ? b : b - B1;
        int e = bb * 256 + threadIdx.x;
        if (e >= E) return;
        int r = row[e];
        if (e == 0) {
            for (int j = 0; j <= r; ++j) ptr[j] = 0;
        }
        int rn = (e == E - 1) ? n : row[e + 1];
        for (int j = r + 1; j <= rn; ++j) ptr[j] = e + 1;
    } else {
        int idx = (b - B1 - B2) * 256 + threadIdx.x;
        if (idx < 16384) {
            int k = idx >> 6, j = idx & 63;
            wt1[j * 256 + k] = f2bf(pw1[idx]);
            wt2[j * 256 + k] = f2bf(pw2[idx]);
        }
        if (idx < 4096) {
            int k = idx >> 6, j = idx & 63;
            wtl1[j * 64 + k] = f2bf(w1[idx]);
            wtl2[j * 64 + k] = f2bf(w2[idx]);
        }
        if (idx < 64) {
            m1z[idx] = 0;
            m2z[idx] = 0;
        }
    }
}

// ---------------------------------------------------------------------------
// K1: msg1/msg2 = bf16(x @ W1/W2) via MFMA. One wave = 16 nodes (M=16,K=64,
// N=64). MFMA 16x16x32 layout (m89): A i=lane&15, k=(lane>>4)*8+e; B j=lane&15;
// D col=lane&15, row=(lane>>4)*4+reg. No LDS, no barriers.
// ---------------------------------------------------------------------------
__global__ __launch_bounds__(512) void linear_mfma(const float* __restrict__ x,
                                                   const ushort* __restrict__ wtl1,
                                                   const ushort* __restrict__ wtl2,
                                                   ushort* __restrict__ m1,
                                                   ushort* __restrict__ m2, int n)
{
    const int tid = threadIdx.x, wv = tid >> 6, lane = tid & 63;
    const int r = lane & 15, c = lane >> 4;
    const int nodebase = blockIdx.x * 128 + wv * 16;
    const int anode = nodebase + r;

    bf16x8 a[2];
#pragma unroll
    for (int kt = 0; kt < 2; ++kt) {
        float4 lo = {0.f, 0.f, 0.f, 0.f}, hi = {0.f, 0.f, 0.f, 0.f};
        if (anode < n) {
            lo = *(const float4*)&x[(size_t)anode * 64 + kt * 32 + c * 8];
            hi = *(const float4*)&x[(size_t)anode * 64 + kt * 32 + c * 8 + 4];
        }
        ushort t[8] = {f2bf(lo.x), f2bf(lo.y), f2bf(lo.z), f2bf(lo.w),
                       f2bf(hi.x), f2bf(hi.y), f2bf(hi.z), f2bf(hi.w)};
        a[kt] = *(const bf16x8*)t;
    }

    f32x4 acc1[4] = {{0.f,0.f,0.f,0.f},{0.f,0.f,0.f,0.f},
                     {0.f,0.f,0.f,0.f},{0.f,0.f,0.f,0.f}};
    f32x4 acc2[4] = {{0.f,0.f,0.f,0.f},{0.f,0.f,0.f,0.f},
                     {0.f,0.f,0.f,0.f},{0.f,0.f,0.f,0.f}};
#pragma unroll
    for (int kt = 0; kt < 2; ++kt) {
#pragma unroll
        for (int nt = 0; nt < 4; ++nt) {
            bf16x8 b1 = *(const bf16x8*)&wtl1[(nt * 16 + r) * 64 + kt * 32 + c * 8];
            bf16x8 b2 = *(const bf16x8*)&wtl2[(nt * 16 + r) * 64 + kt * 32 + c * 8];
            acc1[nt] = __builtin_amdgcn_mfma_f32_16x16x32_bf16(a[kt], b1, acc1[nt], 0, 0, 0);
            acc2[nt] = __builtin_amdgcn_mfma_f32_16x16x32_bf16(a[kt], b2, acc2[nt], 0, 0, 0);
        }
    }

#pragma unroll
    for (int e = 0; e < 4; ++e) {
        const int i = nodebase + c * 4 + e;
        if (i < n) {
#pragma unroll
            for (int nt = 0; nt < 4; ++nt) {
                m1[(size_t)i * 64 + nt * 16 + r] = f2bf(acc1[nt][e]);
                m2[(size_t)i * 64 + nt * 16 + r] = f2bf(acc2[nt][e]);
            }
        }
    }
}

// ---------------------------------------------------------------------------
// PNA aggregation with a depth-2 node pipeline: two NAMED register gather
// buffers (A/B) ping-pong so node nn+1's 8 gathers are issued before node
// nn is consumed -> compiler emits counted vmcnt (16 loads in flight/wave,
// no full drain between nodes). Static indexing throughout (no scratch).
// Scalar (SGPR) col pipeline; invalid slots read zero row n (sum/sq
// unmasked; only max needs validity). Lanes 0-31 = edge slots 0..7,
// lanes 32-63 = slots 8..15; 2 features/lane. deg>16 tail is serial (rare).
// ---------------------------------------------------------------------------
__device__ __forceinline__ void agg_pass(const ushort* __restrict__ msg,
                                         const int* __restrict__ col,
                                         const ushort* __restrict__ wt,
                                         int rpv, ushort (*stw)[256],
                                         f32x4 acc[4],
                                         int nodebase, int lane, int n, int E)
{
    const int half = lane >> 5;
    const int l32 = lane & 31;
    const uint lanoff = (uint)l32 << 2;   // byte offset within a 128B row
    const int jbase = half << 3;          // 0 or 8
    const char* msgc = (const char*)msg;

    uint gvA[8], gvB[8];
    int e0A = 0, cntA = 0, e0B = 0, cntB = 0;

#define ISSUE(nn, gv, e0o, cnto)                                              \
    {                                                                         \
        const int e0_ = __builtin_amdgcn_readlane(rpv, (nn));                 \
        const int e1_ = __builtin_amdgcn_readlane(rpv, (nn) + 1);             \
        const int rem_ = e1_ - e0_;                                           \
        e0o = e0_; cnto = rem_;                                               \
        _Pragma("unroll")                                                     \
        for (int t = 0; t < 8; ++t) {                                         \
            int ilo = e0_ + t;     if (ilo > E - 1) ilo = E - 1;              \
            int ihi = e0_ + t + 8; if (ihi > E - 1) ihi = E - 1;              \
            const int rlo = (t < rem_)     ? col[ilo] : n;                    \
            const int rhi = (t + 8 < rem_) ? col[ihi] : n;                    \
            const int rsel = half ? rhi : rlo;                                \
            gv[t] = *(const uint*)(msgc + (((uint)rsel << 7) + lanoff));      \
        }                                                                     \
    }

#define CONSUME(nn, gv, e0v, cntv)                                            \
    {                                                                         \
        const int cnt = cntv;                                                 \
        float s0 = 0.f, s1 = 0.f, q0 = 0.f, q1 = 0.f;                         \
        float m0 = -INFINITY, m1v = -INFINITY;                                \
        _Pragma("unroll")                                                     \
        for (int t = 0; t < 8; ++t) {                                         \
            const bool valid = (jbase + t) < cnt;                             \
            const float a = bf2f((ushort)(gv[t] & 0xffffu));                  \
            const float b = bf2f((ushort)(gv[t] >> 16));                      \
            s0 += a; q0 = fmaf(a, a, q0);                                     \
            s1 += b; q1 = fmaf(b, b, q1);                                     \
            m0  = fmaxf(m0,  valid ? a : -INFINITY);                          \
            m1v = fmaxf(m1v, valid ? b : -INFINITY);                          \
        }                                                                     \
        if (cnt > 16) { /* wave-uniform rare tail */                          \
            const int e1_ = e0v + cnt;                                        \
            for (int eb = e0v + 16; eb < e1_; eb += 16) {                     \
                const int rem = e1_ - eb;                                     \
                uint gx[8];                                                   \
                _Pragma("unroll")                                             \
                for (int t = 0; t < 8; ++t) {                                 \
                    int ilo = eb + t;     if (ilo > E - 1) ilo = E - 1;       \
                    int ihi = eb + t + 8; if (ihi > E - 1) ihi = E - 1;       \
                    const int rlo = (t < rem)     ? col[ilo] : n;             \
                    const int rhi = (t + 8 < rem) ? col[ihi] : n;             \
                    const int rsel = half ? rhi : rlo;                        \
                    gx[t] = *(const uint*)(msgc + (((uint)rsel << 7) + lanoff));\
                }                                                             \
                _Pragma("unroll")                                             \
                for (int t = 0; t < 8; ++t) {                                 \
                    const bool valid = (jbase + t) < rem;                     \
                    const float a = bf2f((ushort)(gx[t] & 0xffffu));          \
                    const float b = bf2f((ushort)(gx[t] >> 16));              \
                    s0 += a; q0 = fmaf(a, a, q0);                             \
                    s1 += b; q1 = fmaf(b, b, q1);                             \
                    m0  = fmaxf(m0,  valid ? a : -INFINITY);                  \
                    m1v = fmaxf(m1v, valid ? b : -INFINITY);                  \
                }                                                             \
            }                                                                 \
        }                                                                     \
        s0 += __shfl_xor(s0, 32, 64);  s1 += __shfl_xor(s1, 32, 64);          \
        q0 += __shfl_xor(q0, 32, 64);  q1 += __shfl_xor(q1, 32, 64);          \
        m0  = fmaxf(m0,  __shfl_xor(m0, 32, 64));                             \
        m1v = fmaxf(m1v, __shfl_xor(m1v, 32, 64));                            \
        const float cf = (cnt > 0) ? (float)cnt : 1.f;                        \
        const float inv = 1.f / cf;                                           \
        const float mean0 = s0 * inv, mean1 = s1 * inv;                       \
        float v0 = q0 * inv - mean0 * mean0; if (v0 < 0.f) v0 = 0.f;          \
        float v1 = q1 * inv - mean1 * mean1; if (v1 < 0.f) v1 = 0.f;          \
        const float sd0 = sqrtf(v0 + EPS), sd1 = sqrtf(v1 + EPS);             \
        float mm0 = m0, mm1 = m1v;                                            \
        if (cnt == 0) { mm0 = 0.f; mm1 = 0.f; }                               \
        char* rowp = (char*)&stw[(nn)][0];                                    \
        const int sw = ((nn) & 7) << 4;                                       \
        if (half == 0) {                                                      \
            *(uint*)(rowp + ((0 + (int)lanoff) ^ sw))   = cvtpk(s0, s1);      \
            *(uint*)(rowp + ((256 + (int)lanoff) ^ sw)) = cvtpk(mm0, mm1);    \
        } else {                                                              \
            *(uint*)(rowp + ((128 + (int)lanoff) ^ sw)) = cvtpk(mean0, mean1);\
            *(uint*)(rowp + ((384 + (int)lanoff) ^ sw)) = cvtpk(sd0, sd1);    \
        }                                                                     \
    }

    ISSUE(0, gvA, e0A, cntA);
    for (int base = 0; base < 16; base += 2) {
        if (base + 1 < 16) ISSUE(base + 1, gvB, e0B, cntB);
        CONSUME(base, gvA, e0A, cntA);
        if (base + 2 < 16) ISSUE(base + 2, gvA, e0A, cntA);
        if (base + 1 < 16) CONSUME(base + 1, gvB, e0B, cntB);
    }
#undef ISSUE
#undef CONSUME

    // MFMA combine (accumulates into acc)
    const int r = lane & 15, c = lane >> 4;
    const char* arow = (const char*)&stw[r][0];
    const int asw = (r & 7) << 4;
#pragma unroll
    for (int kt = 0; kt < 8; ++kt) {
        bf16x8 a = *(const bf16x8*)(arow + ((kt * 64 + c * 16) ^ asw));
#pragma unroll
        for (int nt = 0; nt < 4; ++nt) {
            bf16x8 b = *(const bf16x8*)&wt[(nt * 16 + r) * 256 + kt * 32 + c * 8];
            acc[nt] = __builtin_amdgcn_mfma_f32_16x16x32_bf16(a, b, acc[nt], 0, 0, 0);
        }
    }
}

// ---------------------------------------------------------------------------
// K2a: PNA pass 1 (graph 1): aggregate + MFMA, write bf16 partial.
// 2 waves/WG, 16 KB LDS. One dispatch per graph keeps gather set L2-friendly.
// ---------------------------------------------------------------------------
__global__ __launch_bounds__(128) void pna_pass1(
    const ushort* __restrict__ msg, const int* __restrict__ rptr,
    const int* __restrict__ col, const ushort* __restrict__ wt,
    ushort* __restrict__ partial, int n, int E)
{
    __shared__ ushort st[2][16][256];  // 16 KB
    const int tid = threadIdx.x;
    const int wv = tid >> 6, lane = tid & 63;
    const int nodebase = blockIdx.x * 32 + wv * 16;

    int rpidx = nodebase + (lane & 31);
    if (rpidx > n) rpidx = n;
    const int rpv = rptr[rpidx];

    f32x4 acc[4] = {{0.f,0.f,0.f,0.f},{0.f,0.f,0.f,0.f},
                    {0.f,0.f,0.f,0.f},{0.f,0.f,0.f,0.f}};

    agg_pass(msg, col, wt, rpv, st[wv], acc, nodebase, lane, n, E);

    const int r = lane & 15, c = lane >> 4;
#pragma unroll
    for (int e = 0; e < 4; ++e) {
        const int i = nodebase + c * 4 + e;
        if (i < n) {
#pragma unroll
            for (int nt = 0; nt < 4; ++nt)
                partial[(size_t)i * 64 + nt * 16 + r] = f2bf(acc[nt][e]);
        }
    }
}

// ---------------------------------------------------------------------------
// K2b: PNA pass 2 (graph 2): aggregate + MFMA, add bf16 partial + biases,
// relu + LayerNorm, write final output.
// ---------------------------------------------------------------------------
__global__ __launch_bounds__(128) void pna_pass2(
    const ushort* __restrict__ msg, const int* __restrict__ rptr,
    const int* __restrict__ col, const ushort* __restrict__ wt,
    const float* __restrict__ b1, const float* __restrict__ b2,
    const float* __restrict__ gamma, const float* __restrict__ beta,
    const ushort* __restrict__ partial, float* __restrict__ out,
    int n, int E)
{
    __shared__ ushort st[2][16][256];  // 16 KB
    const int tid = threadIdx.x;
    const int wv = tid >> 6, lane = tid & 63;
    const int nodebase = blockIdx.x * 32 + wv * 16;

    int rpidx = nodebase + (lane & 31);
    if (rpidx > n) rpidx = n;
    const int rpv = rptr[rpidx];

    f32x4 acc[4] = {{0.f,0.f,0.f,0.f},{0.f,0.f,0.f,0.f},
                    {0.f,0.f,0.f,0.f},{0.f,0.f,0.f,0.f}};

    agg_pass(msg, col, wt, rpv, st[wv], acc, nodebase, lane, n, E);

    const int r = lane & 15, c = lane >> 4;
    float biasv[4], gmv[4], btv[4];
#pragma unroll
    for (int nt = 0; nt < 4; ++nt) {
        biasv[nt] = b1[nt * 16 + r] + b2[nt * 16 + r];
        gmv[nt] = gamma[nt * 16 + r];
        btv[nt] = beta[nt * 16 + r];
    }
#pragma unroll
    for (int e = 0; e < 4; ++e) {
        const int i = nodebase + c * 4 + e;
        float v[4];
        float sum = 0.f;
#pragma unroll
        for (int nt = 0; nt < 4; ++nt) {
            float t = 0.f;
            if (i < n)
                t = fmaxf(acc[nt][e] + biasv[nt] +
                          bf2f(partial[(size_t)i * 64 + nt * 16 + r]), 0.f);
            v[nt] = t;
            sum += t;
        }
        sum += __shfl_xor(sum, 1);
        sum += __shfl_xor(sum, 2);
        sum += __shfl_xor(sum, 4);
        sum += __shfl_xor(sum, 8);
        const float mu = sum * (1.f / 64.f);
        float sqs = 0.f;
#pragma unroll
        for (int nt = 0; nt < 4; ++nt) {
            float d = v[nt] - mu;
            sqs += d * d;
        }
        sqs += __shfl_xor(sqs, 1);
        sqs += __shfl_xor(sqs, 2);
        sqs += __shfl_xor(sqs, 4);
        sqs += __shfl_xor(sqs, 8);
        const float rs = rsqrtf(sqs * (1.f / 64.f) + EPS);
        if (i < n) {
#pragma unroll
            for (int nt = 0; nt < 4; ++nt)
                out[(size_t)i * 64 + nt * 16 + r] =
                    (v[nt] - mu) * rs * gmv[nt] + btv[nt];
        }
    }
}

// ---------------------------------------------------------------------------
extern "C" void kernel_launch(void* const* d_in, const int* in_sizes, int n_in,
                              void* d_out, int out_size, void* d_ws, size_t ws_size,
                              hipStream_t stream)
{
    const float* x     = (const float*)d_in[0];
    const float* w1    = (const float*)d_in[1];
    const float* w2    = (const float*)d_in[2];
    const float* pw1   = (const float*)d_in[3];
    const float* pb1   = (const float*)d_in[4];
    const float* pw2   = (const float*)d_in[5];
    const float* pb2   = (const float*)d_in[6];
    const float* gamma = (const float*)d_in[7];
    const float* beta  = (const float*)d_in[8];
    const int* nb_row  = (const int*)d_in[9];
    const int* nb_col  = (const int*)d_in[10];
    const int* cci_row = (const int*)d_in[11];
    const int* cci_col = (const int*)d_in[12];

    const int n  = in_sizes[0] / 64;   // 100000
    const int E1 = in_sizes[9];        // 1,000,000
    const int E2 = in_sizes[11];

    // workspace: msg1/msg2 bf16 [(n+1)*64] (row n = zeros) | ptr1/ptr2 [n+1] |
    //            wt1/wt2 [16384] | wtl1/wtl2 [4096] | partial bf16 [n*64]
    char* p = (char*)d_ws;
    ushort* msg1 = (ushort*)p;  p += (size_t)(n + 1) * 64 * sizeof(ushort);
    ushort* msg2 = (ushort*)p;  p += (size_t)(n + 1) * 64 * sizeof(ushort);
    int* ptr1 = (int*)p;        p += (size_t)(n + 1) * sizeof(int);
    int* ptr2 = (int*)p;        p += (size_t)(n + 1) * sizeof(int);
    p = (char*)(((uintptr_t)p + 63) & ~(uintptr_t)63);
    ushort* wt1 = (ushort*)p;   p += 16384 * sizeof(ushort);
    ushort* wt2 = (ushort*)p;   p += 16384 * sizeof(ushort);
    ushort* wtl1 = (ushort*)p;  p += 4096 * sizeof(ushort);
    ushort* wtl2 = (ushort*)p;  p += 4096 * sizeof(ushort);
    ushort* partial = (ushort*)p;
    float* outf = (float*)d_out;

    const int B1 = (E1 + 255) / 256, B2 = (E2 + 255) / 256;
    prep_all<<<B1 + B2 + 64, 256, 0, stream>>>(
        nb_row, ptr1, E1, cci_row, ptr2, E2,
        pw1, pw2, w1, w2, wt1, wt2, wtl1, wtl2,
        msg1 + (size_t)n * 64, msg2 + (size_t)n * 64, n, B1, B2);
    linear_mfma<<<(n + 127) / 128, 512, 0, stream>>>(x, wtl1, wtl2, msg1, msg2, n);

    const int grid = (n + 31) / 32;
    pna_pass1<<<grid, 128, 0, stream>>>(msg1, ptr1, nb_col, wt1, partial, n, E1);
    pna_pass2<<<grid, 128, 0, stream>>>(msg2, ptr2, cci_col, wt2,
                                        pb1, pb2, gamma, beta, partial, outf, n, E2);
}

// Round 14
// 135.018 us; speedup vs baseline: 1.2677x; 1.2052x over previous
//
#include <hip/hip_runtime.h>
#include <math.h>

#define EPS 1e-5f

typedef __attribute__((ext_vector_type(8))) short bf16x8;
typedef __attribute__((ext_vector_type(4))) float f32x4;

__device__ __forceinline__ ushort f2bf(float f) {
    union { float f; unsigned u; } v; v.f = f;
    unsigned u = v.u;
    return (ushort)((u + 0x7fffu + ((u >> 16) & 1u)) >> 16);  // RNE
}
__device__ __forceinline__ float bf2f(ushort h) {
    union { unsigned u; float f; } v; v.u = ((unsigned)h) << 16;
    return v.f;
}
__device__ __forceinline__ float bflo(uint u) {
    union { unsigned a; float f; } v; v.a = u << 16;
    return v.f;
}
__device__ __forceinline__ float bfhi(uint u) {
    union { unsigned a; float f; } v; v.a = u & 0xffff0000u;
    return v.f;
}
// packed RNE f32->bf16x2 in one instruction (gfx950 v_cvt_pk_bf16_f32)
__device__ __forceinline__ uint cvtpk(float lo, float hi) {
    uint r;
    asm("v_cvt_pk_bf16_f32 %0, %1, %2" : "=v"(r) : "v"(lo), "v"(hi));
    return r;
}
__device__ __forceinline__ float fast_rcp(float x) {
    float r; asm("v_rcp_f32 %0, %1" : "=v"(r) : "v"(x)); return r;
}
__device__ __forceinline__ float fast_rsq(float x) {
    float r; asm("v_rsq_f32 %0, %1" : "=v"(r) : "v"(x)); return r;
}

// ---------------------------------------------------------------------------
// K0: fused prep — CSR row pointers for both graphs + padded col copies +
// bf16 weight transposes + zero pad rows of msg1/msg2.
// Block ranges: [0,B1) rp1 | [B1,B1+B2) rp2 | [.., +C1) col1 copy |
// [.., +C2) col2 copy | last 64: weights.
// ---------------------------------------------------------------------------
__global__ __launch_bounds__(256) void prep_all(
    const int* __restrict__ row1, int* __restrict__ ptr1, int E1,
    const int* __restrict__ row2, int* __restrict__ ptr2, int E2,
    const int* __restrict__ col1, int* __restrict__ col1p,
    const int* __restrict__ col2, int* __restrict__ col2p,
    const float* __restrict__ pw1, const float* __restrict__ pw2,
    const float* __restrict__ w1, const float* __restrict__ w2,
    ushort* __restrict__ wt1, ushort* __restrict__ wt2,
    ushort* __restrict__ wtl1, ushort* __restrict__ wtl2,
    ushort* __restrict__ m1z, ushort* __restrict__ m2z,
    int n, int B1, int B2, int C1, int C2)
{
    const int b = blockIdx.x;
    if (b < B1 + B2) {
        const int* row = (b < B1) ? row1 : row2;
        int* ptr = (b < B1) ? ptr1 : ptr2;
        const int E = (b < B1) ? E1 : E2;
        const int bb = (b < B1) ? b : b - B1;
        int e = bb * 256 + threadIdx.x;
        if (e >= E) return;
        int r = row[e];
        if (e == 0) {
            for (int j = 0; j <= r; ++j) ptr[j] = 0;
        }
        int rn = (e == E - 1) ? n : row[e + 1];
        for (int j = r + 1; j <= rn; ++j) ptr[j] = e + 1;
    } else if (b < B1 + B2 + C1 + C2) {
        const bool g1 = (b < B1 + B2 + C1);
        const int* src = g1 ? col1 : col2;
        int* dst = g1 ? col1p : col2p;
        const int E = g1 ? E1 : E2;
        const int bb = g1 ? (b - B1 - B2) : (b - B1 - B2 - C1);
        int e = bb * 256 + threadIdx.x;
        if (e < E) dst[e] = src[e];
        else if (e < E + 16) dst[e] = n;   // pad -> zero row
    } else {
        int idx = (b - B1 - B2 - C1 - C2) * 256 + threadIdx.x;
        if (idx < 16384) {
            int k = idx >> 6, j = idx & 63;
            wt1[j * 256 + k] = f2bf(pw1[idx]);
            wt2[j * 256 + k] = f2bf(pw2[idx]);
        }
        if (idx < 4096) {
            int k = idx >> 6, j = idx & 63;
            wtl1[j * 64 + k] = f2bf(w1[idx]);
            wtl2[j * 64 + k] = f2bf(w2[idx]);
        }
        if (idx < 64) {
            m1z[idx] = 0;
            m2z[idx] = 0;
        }
    }
}

// ---------------------------------------------------------------------------
// K1: msg1/msg2 = bf16(x @ W1/W2) via MFMA. One wave = 16 nodes (M=16,K=64,
// N=64). MFMA 16x16x32 layout (m89): A i=lane&15, k=(lane>>4)*8+e; B j=lane&15;
// D col=lane&15, row=(lane>>4)*4+reg. No LDS, no barriers.
// ---------------------------------------------------------------------------
__global__ __launch_bounds__(512) void linear_mfma(const float* __restrict__ x,
                                                   const ushort* __restrict__ wtl1,
                                                   const ushort* __restrict__ wtl2,
                                                   ushort* __restrict__ m1,
                                                   ushort* __restrict__ m2, int n)
{
    const int tid = threadIdx.x, wv = tid >> 6, lane = tid & 63;
    const int r = lane & 15, c = lane >> 4;
    const int nodebase = blockIdx.x * 128 + wv * 16;
    const int anode = nodebase + r;

    bf16x8 a[2];
#pragma unroll
    for (int kt = 0; kt < 2; ++kt) {
        float4 lo = {0.f, 0.f, 0.f, 0.f}, hi = {0.f, 0.f, 0.f, 0.f};
        if (anode < n) {
            lo = *(const float4*)&x[(size_t)anode * 64 + kt * 32 + c * 8];
            hi = *(const float4*)&x[(size_t)anode * 64 + kt * 32 + c * 8 + 4];
        }
        ushort t[8] = {f2bf(lo.x), f2bf(lo.y), f2bf(lo.z), f2bf(lo.w),
                       f2bf(hi.x), f2bf(hi.y), f2bf(hi.z), f2bf(hi.w)};
        a[kt] = *(const bf16x8*)t;
    }

    f32x4 acc1[4] = {{0.f,0.f,0.f,0.f},{0.f,0.f,0.f,0.f},
                     {0.f,0.f,0.f,0.f},{0.f,0.f,0.f,0.f}};
    f32x4 acc2[4] = {{0.f,0.f,0.f,0.f},{0.f,0.f,0.f,0.f},
                     {0.f,0.f,0.f,0.f},{0.f,0.f,0.f,0.f}};
#pragma unroll
    for (int kt = 0; kt < 2; ++kt) {
#pragma unroll
        for (int nt = 0; nt < 4; ++nt) {
            bf16x8 b1 = *(const bf16x8*)&wtl1[(nt * 16 + r) * 64 + kt * 32 + c * 8];
            bf16x8 b2 = *(const bf16x8*)&wtl2[(nt * 16 + r) * 64 + kt * 32 + c * 8];
            acc1[nt] = __builtin_amdgcn_mfma_f32_16x16x32_bf16(a[kt], b1, acc1[nt], 0, 0, 0);
            acc2[nt] = __builtin_amdgcn_mfma_f32_16x16x32_bf16(a[kt], b2, acc2[nt], 0, 0, 0);
        }
    }

#pragma unroll
    for (int e = 0; e < 4; ++e) {
        const int i = nodebase + c * 4 + e;
        if (i < n) {
#pragma unroll
            for (int nt = 0; nt < 4; ++nt) {
                m1[(size_t)i * 64 + nt * 16 + r] = f2bf(acc1[nt][e]);
                m2[(size_t)i * 64 + nt * 16 + r] = f2bf(acc2[nt][e]);
            }
        }
    }
}

// ---------------------------------------------------------------------------
// PNA aggregation, quad-node layout: 4 nodes concurrently per wave
// (16 lanes/node; lane owns 4 features, 8B dwordx2 gathers). One batch =
// 16 slots x 4 nodes = 64 lines in flight per wave; col indices come from a
// PADDED col copy via vector loads (no scalar chain, no clamps). Invalid
// slots gather zero row n (sum/sq unmasked; max cndmask'd). No cross-lane
// reduction. Stats -> swizzled LDS rows (same layout as before) -> MFMA.
// ---------------------------------------------------------------------------
__device__ __forceinline__ void agg_pass(const ushort* __restrict__ msg,
                                         const int* __restrict__ colp,
                                         const ushort* __restrict__ wt,
                                         int rpv, ushort (*stw)[256],
                                         f32x4 acc[4],
                                         int nodebase, int lane, int n, int E)
{
    const int grp = lane >> 4;        // node within quad
    const int fq  = lane & 15;        // feature quad: features 4fq..4fq+3
    const uint fqb = (uint)fq << 3;   // byte offset within 128B row
    const char* msgc = (const char*)msg;

    for (int qd = 0; qd < 4; ++qd) {
        const int b0 = __builtin_amdgcn_readlane(rpv, 4 * qd);
        const int b1 = __builtin_amdgcn_readlane(rpv, 4 * qd + 1);
        const int b2 = __builtin_amdgcn_readlane(rpv, 4 * qd + 2);
        const int b3 = __builtin_amdgcn_readlane(rpv, 4 * qd + 3);
        const int b4 = __builtin_amdgcn_readlane(rpv, 4 * qd + 4);
        int e0 = (grp & 1) ? b1 : b0;
        int eA = (grp & 1) ? b3 : b2;
        e0 = (grp & 2) ? eA : e0;
        int e1 = (grp & 1) ? b2 : b1;
        int eB = (grp & 1) ? b4 : b3;
        e1 = (grp & 2) ? eB : e1;
        const int cnt = e1 - e0;      // lane-group uniform

        float s0 = 0.f, s1 = 0.f, s2 = 0.f, s3 = 0.f;
        float q0 = 0.f, q1 = 0.f, q2 = 0.f, q3 = 0.f;
        float m0 = -INFINITY, m1v = -INFINITY, m2v = -INFINITY, m3 = -INFINITY;

        for (int off = 0; ; off += 16) {
            const int* cwin = colp + e0 + off;   // padded: e0+off+15 < E+16
            uint cv[16];
#pragma unroll
            for (int t = 0; t < 16; ++t) cv[t] = ((const uint*)cwin)[t];

            uint2 gv[16];
#pragma unroll
            for (int t = 0; t < 16; ++t) {
                const bool valid = (off + t) < cnt;
                const uint row = valid ? cv[t] : (uint)n;
                gv[t] = *(const uint2*)(msgc + (((size_t)row << 7) + fqb));
            }
#pragma unroll
            for (int t = 0; t < 16; ++t) {
                const bool valid = (off + t) < cnt;
                const float f0 = bflo(gv[t].x), f1 = bfhi(gv[t].x);
                const float f2 = bflo(gv[t].y), f3 = bfhi(gv[t].y);
                s0 += f0; q0 = fmaf(f0, f0, q0);
                s1 += f1; q1 = fmaf(f1, f1, q1);
                s2 += f2; q2 = fmaf(f2, f2, q2);
                s3 += f3; q3 = fmaf(f3, f3, q3);
                m0  = fmaxf(m0,  valid ? f0 : -INFINITY);
                m1v = fmaxf(m1v, valid ? f1 : -INFINITY);
                m2v = fmaxf(m2v, valid ? f2 : -INFINITY);
                m3  = fmaxf(m3,  valid ? f3 : -INFINITY);
            }
            if (!__any(cnt > off + 16)) break;
        }

        // finalize (fast rcp/rsq; bf16-accuracy sufficient)
        const float cf = (cnt > 0) ? (float)cnt : 1.f;
        const float inv = fast_rcp(cf);
        const float mean0 = s0 * inv, mean1 = s1 * inv;
        const float mean2 = s2 * inv, mean3 = s3 * inv;
        float v0 = q0 * inv - mean0 * mean0; if (v0 < 0.f) v0 = 0.f;
        float v1 = q1 * inv - mean1 * mean1; if (v1 < 0.f) v1 = 0.f;
        float v2 = q2 * inv - mean2 * mean2; if (v2 < 0.f) v2 = 0.f;
        float v3 = q3 * inv - mean3 * mean3; if (v3 < 0.f) v3 = 0.f;
        const float sd0 = (v0 + EPS) * fast_rsq(v0 + EPS);
        const float sd1 = (v1 + EPS) * fast_rsq(v1 + EPS);
        const float sd2 = (v2 + EPS) * fast_rsq(v2 + EPS);
        const float sd3 = (v3 + EPS) * fast_rsq(v3 + EPS);
        if (cnt == 0) { m0 = 0.f; m1v = 0.f; m2v = 0.f; m3 = 0.f; }

        // store 4 stat blocks (feature f at byte 2f within block, XOR swizzle)
        const int nn = 4 * qd + grp;
        char* rowp = (char*)&stw[nn][0];
        const int sw = (nn & 7) << 4;
        uint2 w;
        w.x = cvtpk(s0, s1);       w.y = cvtpk(s2, s3);
        *(uint2*)(rowp + ((0   + (int)fqb) ^ sw)) = w;
        w.x = cvtpk(mean0, mean1); w.y = cvtpk(mean2, mean3);
        *(uint2*)(rowp + ((128 + (int)fqb) ^ sw)) = w;
        w.x = cvtpk(m0, m1v);      w.y = cvtpk(m2v, m3);
        *(uint2*)(rowp + ((256 + (int)fqb) ^ sw)) = w;
        w.x = cvtpk(sd0, sd1);     w.y = cvtpk(sd2, sd3);
        *(uint2*)(rowp + ((384 + (int)fqb) ^ sw)) = w;
    }

    // MFMA combine (accumulates into acc) — layout unchanged from r13
    const int r = lane & 15, c = lane >> 4;
    const char* arow = (const char*)&stw[r][0];
    const int asw = (r & 7) << 4;
#pragma unroll
    for (int kt = 0; kt < 8; ++kt) {
        bf16x8 a = *(const bf16x8*)(arow + ((kt * 64 + c * 16) ^ asw));
#pragma unroll
        for (int nt = 0; nt < 4; ++nt) {
            bf16x8 b = *(const bf16x8*)&wt[(nt * 16 + r) * 256 + kt * 32 + c * 8];
            acc[nt] = __builtin_amdgcn_mfma_f32_16x16x32_bf16(a, b, acc[nt], 0, 0, 0);
        }
    }
}

// ---------------------------------------------------------------------------
// K2a: PNA pass 1 (graph 1): aggregate + MFMA, write bf16 partial.
// ---------------------------------------------------------------------------
__global__ __launch_bounds__(128) void pna_pass1(
    const ushort* __restrict__ msg, const int* __restrict__ rptr,
    const int* __restrict__ colp, const ushort* __restrict__ wt,
    ushort* __restrict__ partial, int n, int E)
{
    __shared__ ushort st[2][16][256];  // 16 KB
    const int tid = threadIdx.x;
    const int wv = tid >> 6, lane = tid & 63;
    const int nodebase = blockIdx.x * 32 + wv * 16;

    int rpidx = nodebase + (lane & 31);
    if (rpidx > n) rpidx = n;
    const int rpv = rptr[rpidx];

    f32x4 acc[4] = {{0.f,0.f,0.f,0.f},{0.f,0.f,0.f,0.f},
                    {0.f,0.f,0.f,0.f},{0.f,0.f,0.f,0.f}};

    agg_pass(msg, colp, wt, rpv, st[wv], acc, nodebase, lane, n, E);

    const int r = lane & 15, c = lane >> 4;
#pragma unroll
    for (int e = 0; e < 4; ++e) {
        const int i = nodebase + c * 4 + e;
        if (i < n) {
#pragma unroll
            for (int nt = 0; nt < 4; ++nt)
                partial[(size_t)i * 64 + nt * 16 + r] = f2bf(acc[nt][e]);
        }
    }
}

// ---------------------------------------------------------------------------
// K2b: PNA pass 2 (graph 2): aggregate + MFMA, add bf16 partial + biases,
// relu + LayerNorm, write final output.
// ---------------------------------------------------------------------------
__global__ __launch_bounds__(128) void pna_pass2(
    const ushort* __restrict__ msg, const int* __restrict__ rptr,
    const int* __restrict__ colp, const ushort* __restrict__ wt,
    const float* __restrict__ b1, const float* __restrict__ b2,
    const float* __restrict__ gamma, const float* __restrict__ beta,
    const ushort* __restrict__ partial, float* __restrict__ out,
    int n, int E)
{
    __shared__ ushort st[2][16][256];  // 16 KB
    const int tid = threadIdx.x;
    const int wv = tid >> 6, lane = tid & 63;
    const int nodebase = blockIdx.x * 32 + wv * 16;

    int rpidx = nodebase + (lane & 31);
    if (rpidx > n) rpidx = n;
    const int rpv = rptr[rpidx];

    f32x4 acc[4] = {{0.f,0.f,0.f,0.f},{0.f,0.f,0.f,0.f},
                    {0.f,0.f,0.f,0.f},{0.f,0.f,0.f,0.f}};

    agg_pass(msg, colp, wt, rpv, st[wv], acc, nodebase, lane, n, E);

    const int r = lane & 15, c = lane >> 4;
    float biasv[4], gmv[4], btv[4];
#pragma unroll
    for (int nt = 0; nt < 4; ++nt) {
        biasv[nt] = b1[nt * 16 + r] + b2[nt * 16 + r];
        gmv[nt] = gamma[nt * 16 + r];
        btv[nt] = beta[nt * 16 + r];
    }
#pragma unroll
    for (int e = 0; e < 4; ++e) {
        const int i = nodebase + c * 4 + e;
        float v[4];
        float sum = 0.f;
#pragma unroll
        for (int nt = 0; nt < 4; ++nt) {
            float t = 0.f;
            if (i < n)
                t = fmaxf(acc[nt][e] + biasv[nt] +
                          bf2f(partial[(size_t)i * 64 + nt * 16 + r]), 0.f);
            v[nt] = t;
            sum += t;
        }
        sum += __shfl_xor(sum, 1);
        sum += __shfl_xor(sum, 2);
        sum += __shfl_xor(sum, 4);
        sum += __shfl_xor(sum, 8);
        const float mu = sum * (1.f / 64.f);
        float sqs = 0.f;
#pragma unroll
        for (int nt = 0; nt < 4; ++nt) {
            float d = v[nt] - mu;
            sqs += d * d;
        }
        sqs += __shfl_xor(sqs, 1);
        sqs += __shfl_xor(sqs, 2);
        sqs += __shfl_xor(sqs, 4);
        sqs += __shfl_xor(sqs, 8);
        const float rs = rsqrtf(sqs * (1.f / 64.f) + EPS);
        if (i < n) {
#pragma unroll
            for (int nt = 0; nt < 4; ++nt)
                out[(size_t)i * 64 + nt * 16 + r] =
                    (v[nt] - mu) * rs * gmv[nt] + btv[nt];
        }
    }
}

// ---------------------------------------------------------------------------
extern "C" void kernel_launch(void* const* d_in, const int* in_sizes, int n_in,
                              void* d_out, int out_size, void* d_ws, size_t ws_size,
                              hipStream_t stream)
{
    const float* x     = (const float*)d_in[0];
    const float* w1    = (const float*)d_in[1];
    const float* w2    = (const float*)d_in[2];
    const float* pw1   = (const float*)d_in[3];
    const float* pb1   = (const float*)d_in[4];
    const float* pw2   = (const float*)d_in[5];
    const float* pb2   = (const float*)d_in[6];
    const float* gamma = (const float*)d_in[7];
    const float* beta  = (const float*)d_in[8];
    const int* nb_row  = (const int*)d_in[9];
    const int* nb_col  = (const int*)d_in[10];
    const int* cci_row = (const int*)d_in[11];
    const int* cci_col = (const int*)d_in[12];

    const int n  = in_sizes[0] / 64;   // 100000
    const int E1 = in_sizes[9];        // 1,000,000
    const int E2 = in_sizes[11];

    // workspace: msg1/msg2 bf16 [(n+1)*64] (row n = zeros) | ptr1/ptr2 [n+1] |
    //            wt1/wt2 [16384] | wtl1/wtl2 [4096] | partial bf16 [n*64] |
    //            col1p [E1+16] | col2p [E2+16]   (~47 MB total)
    char* p = (char*)d_ws;
    ushort* msg1 = (ushort*)p;  p += (size_t)(n + 1) * 64 * sizeof(ushort);
    ushort* msg2 = (ushort*)p;  p += (size_t)(n + 1) * 64 * sizeof(ushort);
    int* ptr1 = (int*)p;        p += (size_t)(n + 1) * sizeof(int);
    int* ptr2 = (int*)p;        p += (size_t)(n + 1) * sizeof(int);
    p = (char*)(((uintptr_t)p + 63) & ~(uintptr_t)63);
    ushort* wt1 = (ushort*)p;   p += 16384 * sizeof(ushort);
    ushort* wt2 = (ushort*)p;   p += 16384 * sizeof(ushort);
    ushort* wtl1 = (ushort*)p;  p += 4096 * sizeof(ushort);
    ushort* wtl2 = (ushort*)p;  p += 4096 * sizeof(ushort);
    ushort* partial = (ushort*)p; p += (size_t)n * 64 * sizeof(ushort);
    p = (char*)(((uintptr_t)p + 63) & ~(uintptr_t)63);
    int* col1p = (int*)p;       p += (size_t)(E1 + 16) * sizeof(int);
    int* col2p = (int*)p;
    float* outf = (float*)d_out;

    const int B1 = (E1 + 255) / 256, B2 = (E2 + 255) / 256;
    const int C1 = (E1 + 16 + 255) / 256, C2 = (E2 + 16 + 255) / 256;
    prep_all<<<B1 + B2 + C1 + C2 + 64, 256, 0, stream>>>(
        nb_row, ptr1, E1, cci_row, ptr2, E2,
        nb_col, col1p, cci_col, col2p,
        pw1, pw2, w1, w2, wt1, wt2, wtl1, wtl2,
        msg1 + (size_t)n * 64, msg2 + (size_t)n * 64, n, B1, B2, C1, C2);
    linear_mfma<<<(n + 127) / 128, 512, 0, stream>>>(x, wtl1, wtl2, msg1, msg2, n);

    const int grid = (n + 31) / 32;
    pna_pass1<<<grid, 128, 0, stream>>>(msg1, ptr1, col1p, wt1, partial, n, E1);
    pna_pass2<<<grid, 128, 0, stream>>>(msg2, ptr2, col2p, wt2,
                                        pb1, pb2, gamma, beta, partial, outf, n, E2);
}